// Round 1
// baseline (13851.831 us; speedup 1.0000x reference)
//
#include <hip/hip_runtime.h>

typedef unsigned short ushort_t;
typedef __attribute__((ext_vector_type(8))) short short8;   // 8 bf16 in 4 VGPRs
typedef __attribute__((ext_vector_type(4))) float f32x4;

#define B_ 32
#define T_ 512
#define H_ 512
#define G_ 32      // workgroups per GRU layer
#define CH_ 16     // output channels per workgroup (G_*CH_ == H_)

// ---------- bf16 helpers ----------
__device__ __forceinline__ float bf2f(ushort_t u) {
  union { unsigned int i; float f; } v; v.i = ((unsigned int)u) << 16; return v.f;
}
__device__ __forceinline__ ushort_t f2bf(float f) {
  union { float fv; unsigned int i; } v; v.fv = f;
  unsigned int x = v.i;
  x += 0x7fffu + ((x >> 16) & 1u);   // round-to-nearest-even
  return (ushort_t)(x >> 16);
}

// ---------- prep: fp32 weights -> bf16 ----------
__global__ void prep_w(const float* __restrict__ Wih, const float* __restrict__ Whh,
                       ushort_t* __restrict__ WihBf, ushort_t* __restrict__ WhhBf) {
  int i = blockIdx.x * 256 + threadIdx.x;   // grid sized exactly
  WihBf[i] = f2bf(Wih[i]);
  WhhBf[i] = f2bf(Whh[i]);
}

// ---------- prep: x [B][T][H] fp32 -> [T][B][H] bf16 ----------
__global__ void prep_x(const float* __restrict__ x, ushort_t* __restrict__ xA) {
  int i = blockIdx.x * 256 + threadIdx.x;   // linear over output, h contiguous both sides
  int h  = i & (H_ - 1);
  int tb = i >> 9;
  int b  = tb & (B_ - 1);
  int t  = tb >> 5;
  xA[i] = f2bf(x[((size_t)b * T_ + t) * H_ + h]);
}

// ---------- one GRU layer: persistent, 32 WGs, flag-synced per timestep ----------
// xin/xout: [T][B][H] bf16.  hbuf: [2][B][H] bf16 ping-pong (buf0 pre-zeroed).
// flags: [T] ints pre-zeroed; flags[s]==G_ means h(s+1) fully written.
__global__ __launch_bounds__(256, 1) void gru_layer(
    const ushort_t* __restrict__ xin,
    ushort_t* __restrict__ xout,
    const ushort_t* __restrict__ Wih,   // [3H][H] bf16, gate order r,z,n
    const ushort_t* __restrict__ Whh,
    const float* __restrict__ bih,      // [3H] fp32
    const float* __restrict__ bhh,
    ushort_t* __restrict__ hbuf,
    int* __restrict__ flags)
{
  const int tid   = threadIdx.x;
  const int lane  = tid & 63;
  const int wave  = tid >> 6;          // 0..3: waves 0,1 = x-GEMM, waves 2,3 = h-GEMM
  const int wg    = blockIdx.x;        // 0..31
  const int jb    = wg * CH_;          // channel base
  const int m16   = lane & 15;
  const int quad  = lane >> 4;
  const int ntile = wave & 1;          // batch half
  const int bcol  = ntile * 16 + m16;  // batch column 0..31

  __shared__ float Gx[48][33];         // [gate*16+ch][batch], +1 pad
  __shared__ float Gh[48][33];
  __shared__ float hprev[CH_][B_];     // our channels' h in fp32

  hprev[tid >> 5][tid & 31]       = 0.0f;
  hprev[8 + (tid >> 5)][tid & 31] = 0.0f;

  // A fragments resident in registers: 3 gate-tiles x 16 k-steps, 16B each.
  // mfma_f32_16x16x32_bf16 A layout: A[m=lane&15][k=quad*8+j]
  const ushort_t* Wsel = (wave < 2) ? Wih : Whh;
  short8 afrag[3][16];
#pragma unroll
  for (int g = 0; g < 3; ++g) {
    const ushort_t* wp = Wsel + (size_t)(g * H_ + jb + m16) * H_ + quad * 8;
#pragma unroll
    for (int kk = 0; kk < 16; ++kk)
      afrag[g][kk] = *(const short8*)(wp + kk * 32);
  }

  // Gate-math mapping: thread handles (c0,b0) and (c1,b0)
  const int b0 = tid & 31;
  const int c0 = tid >> 5;      // 0..7
  const int c1 = c0 + 8;
  const float bxr0 = bih[0*H_ + jb + c0], bhr0 = bhh[0*H_ + jb + c0];
  const float bxz0 = bih[1*H_ + jb + c0], bhz0 = bhh[1*H_ + jb + c0];
  const float bxn0 = bih[2*H_ + jb + c0], bhn0 = bhh[2*H_ + jb + c0];
  const float bxr1 = bih[0*H_ + jb + c1], bhr1 = bhh[0*H_ + jb + c1];
  const float bxz1 = bih[1*H_ + jb + c1], bhz1 = bhh[1*H_ + jb + c1];
  const float bxn1 = bih[2*H_ + jb + c1], bhn1 = bhh[2*H_ + jb + c1];

  __syncthreads();

  for (int s = 0; s < T_; ++s) {
    f32x4 acc0 = {0.f, 0.f, 0.f, 0.f};
    f32x4 acc1 = acc0, acc2 = acc0;

    if (wave < 2) {
      // x-GEMM: input written by a previous kernel launch -> no intra-kernel wait
      const ushort_t* src = xin + ((size_t)s * B_ + bcol) * H_ + quad * 8;
#pragma unroll
      for (int kk = 0; kk < 16; ++kk) {
        short8 bf = *(const short8*)(src + kk * 32);
        acc0 = __builtin_amdgcn_mfma_f32_16x16x32_bf16(afrag[0][kk], bf, acc0, 0, 0, 0);
        acc1 = __builtin_amdgcn_mfma_f32_16x16x32_bf16(afrag[1][kk], bf, acc1, 0, 0, 0);
        acc2 = __builtin_amdgcn_mfma_f32_16x16x32_bf16(afrag[2][kk], bf, acc2, 0, 0, 0);
      }
    } else {
      // h-GEMM: wait for all WGs to have published h(s)
      if (s > 0) {
        int* fp = flags + (s - 1);
        while (__hip_atomic_load(fp, __ATOMIC_RELAXED, __HIP_MEMORY_SCOPE_AGENT) < G_)
          __builtin_amdgcn_s_sleep(1);
      }
      __builtin_amdgcn_fence(__ATOMIC_ACQUIRE, "agent");  // invalidate stale L1/L2
      const ushort_t* src = hbuf + ((size_t)(s & 1) * B_ + bcol) * H_ + quad * 8;
#pragma unroll
      for (int kk = 0; kk < 16; ++kk) {
        short8 bf = *(const short8*)(src + kk * 32);
        acc0 = __builtin_amdgcn_mfma_f32_16x16x32_bf16(afrag[0][kk], bf, acc0, 0, 0, 0);
        acc1 = __builtin_amdgcn_mfma_f32_16x16x32_bf16(afrag[1][kk], bf, acc1, 0, 0, 0);
        acc2 = __builtin_amdgcn_mfma_f32_16x16x32_bf16(afrag[2][kk], bf, acc2, 0, 0, 0);
      }
    }

    // C/D layout: col = lane&15 (batch), row = quad*4 + reg
    float (*Gd)[33] = (wave < 2) ? Gx : Gh;
#pragma unroll
    for (int r = 0; r < 4; ++r) {
      Gd[ 0 + quad * 4 + r][bcol] = acc0[r];
      Gd[16 + quad * 4 + r][bcol] = acc1[r];
      Gd[32 + quad * 4 + r][bcol] = acc2[r];
    }
    __syncthreads();

    // Gate math (torch GRU, gate order r,z,n): n = tanh(xn + r*hn)
    ushort_t* hdst = hbuf + (size_t)((s + 1) & 1) * B_ * H_;
    {
      float rr = 1.f / (1.f + __expf(-(Gx[c0][b0] + bxr0 + Gh[c0][b0] + bhr0)));
      float zz = 1.f / (1.f + __expf(-(Gx[16 + c0][b0] + bxz0 + Gh[16 + c0][b0] + bhz0)));
      float nn = tanhf(Gx[32 + c0][b0] + bxn0 + rr * (Gh[32 + c0][b0] + bhn0));
      float hv = (1.f - zz) * nn + zz * hprev[c0][b0];
      hprev[c0][b0] = hv;
      ushort_t hb = f2bf(hv);
      hdst[b0 * H_ + jb + c0] = hb;
      xout[((size_t)s * B_ + b0) * H_ + jb + c0] = hb;
    }
    {
      float rr = 1.f / (1.f + __expf(-(Gx[c1][b0] + bxr1 + Gh[c1][b0] + bhr1)));
      float zz = 1.f / (1.f + __expf(-(Gx[16 + c1][b0] + bxz1 + Gh[16 + c1][b0] + bhz1)));
      float nn = tanhf(Gx[32 + c1][b0] + bxn1 + rr * (Gh[32 + c1][b0] + bhn1));
      float hv = (1.f - zz) * nn + zz * hprev[c1][b0];
      hprev[c1][b0] = hv;
      ushort_t hb = f2bf(hv);
      hdst[b0 * H_ + jb + c1] = hb;
      xout[((size_t)s * B_ + b0) * H_ + jb + c1] = hb;
    }
    __syncthreads();  // drains vmcnt: all h stores in L2 before publish

    if (tid == 0) {
      __builtin_amdgcn_fence(__ATOMIC_RELEASE, "agent");  // writeback L2 -> LLC
      __hip_atomic_fetch_add(flags + s, 1, __ATOMIC_RELAXED, __HIP_MEMORY_SCOPE_AGENT);
    }
  }
}

// ---------- mask (t >= len -> 0) + LayerNorm over H ----------
// mode 0: bf16 out, same [T][B][H] layout.  mode 1: fp32 out to d_out [B][T][H].
__global__ __launch_bounds__(256) void ln_mask(
    const ushort_t* __restrict__ xin,
    ushort_t* __restrict__ xout_bf,
    float* __restrict__ out_f32,
    const float* __restrict__ gamma,
    const float* __restrict__ beta,
    const int* __restrict__ seq_lens,
    int mode)
{
  const int lane = threadIdx.x & 63;
  const int wave = threadIdx.x >> 6;
  const int row  = blockIdx.x * 4 + wave;   // row = t*B_ + b
  const int t = row >> 5;
  const int b = row & 31;
  const int h0 = lane * 8;
  const bool valid = t < seq_lens[b];

  short8 raw = *(const short8*)(xin + (size_t)row * H_ + h0);
  float v[8];
#pragma unroll
  for (int j = 0; j < 8; ++j)
    v[j] = valid ? bf2f((ushort_t)raw[j]) : 0.f;

  float sum = 0.f, sq = 0.f;
#pragma unroll
  for (int j = 0; j < 8; ++j) { sum += v[j]; sq += v[j] * v[j]; }
#pragma unroll
  for (int off = 32; off > 0; off >>= 1) {
    sum += __shfl_xor(sum, off);
    sq  += __shfl_xor(sq, off);
  }
  float mu   = sum * (1.f / H_);
  float var  = sq * (1.f / H_) - mu * mu;
  float rstd = rsqrtf(var + 1e-5f);

  if (mode == 0) {
    short8 o;
#pragma unroll
    for (int j = 0; j < 8; ++j)
      o[j] = (short)f2bf((v[j] - mu) * rstd * gamma[h0 + j] + beta[h0 + j]);
    *(short8*)(xout_bf + (size_t)row * H_ + h0) = o;
  } else {
    float* dst = out_f32 + ((size_t)b * T_ + t) * H_ + h0;
#pragma unroll
    for (int j = 0; j < 8; ++j)
      dst[j] = (v[j] - mu) * rstd * gamma[h0 + j] + beta[h0 + j];
  }
}

// ---------- workspace layout (bytes) ----------
#define WIH_OFF 0u
#define WHH_OFF 6291456u            // 4*1536*512*2
#define XA_OFF  12582912u
#define XB_OFF  29360128u           // XA + 512*32*512*2
#define HB_OFF  46137344u           // XB + 16777216
#define FL_OFF  46399488u           // HB + 4*2*32*512*2
// total = 46407680 bytes (~44.3 MB)

extern "C" void kernel_launch(void* const* d_in, const int* in_sizes, int n_in,
                              void* d_out, int out_size, void* d_ws, size_t ws_size,
                              hipStream_t stream) {
  (void)in_sizes; (void)n_in; (void)out_size; (void)ws_size;
  const float* x     = (const float*)d_in[0];
  const float* Wih   = (const float*)d_in[1];
  const float* Whh   = (const float*)d_in[2];
  const float* bih   = (const float*)d_in[3];
  const float* bhh   = (const float*)d_in[4];
  const float* gamma = (const float*)d_in[5];
  const float* beta  = (const float*)d_in[6];
  const int*   seq   = (const int*)d_in[7];

  char* ws = (char*)d_ws;
  ushort_t* WihBf = (ushort_t*)(ws + WIH_OFF);
  ushort_t* WhhBf = (ushort_t*)(ws + WHH_OFF);
  ushort_t* xA    = (ushort_t*)(ws + XA_OFF);
  ushort_t* xB    = (ushort_t*)(ws + XB_OFF);
  ushort_t* hbuf  = (ushort_t*)(ws + HB_OFF);
  int*      flags = (int*)(ws + FL_OFF);

  // zero h ping-pong buffers + flags (harness poisons ws with 0xAA)
  hipMemsetAsync(ws + HB_OFF, 0, (FL_OFF - HB_OFF) + 4 * 512 * 4, stream);

  prep_w<<<3145728 / 256, 256, 0, stream>>>(Wih, Whh, WihBf, WhhBf);
  prep_x<<<8388608 / 256, 256, 0, stream>>>(x, xA);

  const int WM = 1536 * 512;  // elems per weight matrix
  // layer 0: xA -> xB
  gru_layer<<<G_, 256, 0, stream>>>(xA, xB, WihBf + 0 * WM, WhhBf + 0 * WM,
                                    bih + 0 * 1536, bhh + 0 * 1536,
                                    hbuf + 0 * 32768, flags + 0 * 512);
  // layer 1: xB -> xA
  gru_layer<<<G_, 256, 0, stream>>>(xB, xA, WihBf + 1 * WM, WhhBf + 1 * WM,
                                    bih + 1 * 1536, bhh + 1 * 1536,
                                    hbuf + 1 * 32768, flags + 1 * 512);
  // module 0 mask + LN: xA -> xB (bf16)
  ln_mask<<<4096, 256, 0, stream>>>(xA, xB, nullptr, gamma, beta, seq, 0);
  // layer 2: xB -> xA
  gru_layer<<<G_, 256, 0, stream>>>(xB, xA, WihBf + 2 * WM, WhhBf + 2 * WM,
                                    bih + 2 * 1536, bhh + 2 * 1536,
                                    hbuf + 2 * 32768, flags + 2 * 512);
  // layer 3: xA -> xB
  gru_layer<<<G_, 256, 0, stream>>>(xA, xB, WihBf + 3 * WM, WhhBf + 3 * WM,
                                    bih + 3 * 1536, bhh + 3 * 1536,
                                    hbuf + 3 * 32768, flags + 3 * 512);
  // module 1 mask + LN -> d_out fp32 [B][T][H]
  ln_mask<<<4096, 256, 0, stream>>>(xB, nullptr, (float*)d_out,
                                    gamma + 512, beta + 512, seq, 1);
}

// Round 2
// 13548.357 us; speedup vs baseline: 1.0224x; 1.0224x over previous
//
#include <hip/hip_runtime.h>

typedef unsigned short ushort_t;
typedef __attribute__((ext_vector_type(8))) short short8;   // 8 bf16 in 4 VGPRs
typedef __attribute__((ext_vector_type(4))) float f32x4;

#define B_ 32
#define T_ 512
#define H_ 512
#define G_ 32      // workgroups per GRU layer
#define CH_ 16     // output channels per workgroup (G_*CH_ == H_)

// ---------- bf16 helpers ----------
__device__ __forceinline__ float bf2f(ushort_t u) {
  union { unsigned int i; float f; } v; v.i = ((unsigned int)u) << 16; return v.f;
}
__device__ __forceinline__ ushort_t f2bf(float f) {
  union { float fv; unsigned int i; } v; v.fv = f;
  unsigned int x = v.i;
  x += 0x7fffu + ((x >> 16) & 1u);   // round-to-nearest-even
  return (ushort_t)(x >> 16);
}

// ---------- prep: fp32 weights -> bf16 ----------
__global__ void prep_w(const float* __restrict__ Wih, const float* __restrict__ Whh,
                       ushort_t* __restrict__ WihBf, ushort_t* __restrict__ WhhBf) {
  int i = blockIdx.x * 256 + threadIdx.x;   // grid sized exactly
  WihBf[i] = f2bf(Wih[i]);
  WhhBf[i] = f2bf(Whh[i]);
}

// ---------- prep: x [B][T][H] fp32 -> [T][B][H] bf16 ----------
__global__ void prep_x(const float* __restrict__ x, ushort_t* __restrict__ xA) {
  int i = blockIdx.x * 256 + threadIdx.x;   // linear over output, h contiguous both sides
  int h  = i & (H_ - 1);
  int tb = i >> 9;
  int b  = tb & (B_ - 1);
  int t  = tb >> 5;
  xA[i] = f2bf(x[((size_t)b * T_ + t) * H_ + h]);
}

// ---------- one GRU layer: persistent, 32 WGs, flag-synced per timestep ----------
// Cross-WG exchange (h ping-pong + flags) uses relaxed AGENT-scope atomics ->
// sc-flagged global ops that bypass non-coherent L1/L2 and hit the LLC.
// NO cache-wide fences (round-1's agent fences cost ~7us/step in buffer_inv/
// buffer_wbl2 and evicted the register/L2-resident weights every step).
__global__ __launch_bounds__(256, 1) void gru_layer(
    const ushort_t* __restrict__ xin,
    ushort_t* __restrict__ xout,
    const ushort_t* __restrict__ Wih,   // [3H][H] bf16, gate order r,z,n
    const ushort_t* __restrict__ Whh,
    const float* __restrict__ bih,      // [3H] fp32
    const float* __restrict__ bhh,
    ushort_t* __restrict__ hbuf,
    int* __restrict__ flags)
{
  const int tid   = threadIdx.x;
  const int lane  = tid & 63;
  const int wave  = tid >> 6;          // 0..3: waves 0,1 = x-GEMM, waves 2,3 = h-GEMM
  const int wg    = blockIdx.x;        // 0..31
  const int jb    = wg * CH_;          // channel base
  const int m16   = lane & 15;
  const int quad  = lane >> 4;
  const int ntile = wave & 1;          // batch half
  const int bcol  = ntile * 16 + m16;  // batch column 0..31

  __shared__ float Gx[48][33];         // [gate*16+ch][batch], +1 pad
  __shared__ float Gh[48][33];
  __shared__ float hprev[CH_][B_];     // our channels' h in fp32

  hprev[tid >> 5][tid & 31]       = 0.0f;
  hprev[8 + (tid >> 5)][tid & 31] = 0.0f;

  // A fragments resident in registers: 3 gate-tiles x 16 k-steps, 16B each.
  // mfma_f32_16x16x32_bf16 A layout: A[m=lane&15][k=quad*8+j]
  const ushort_t* Wsel = (wave < 2) ? Wih : Whh;
  short8 afrag[3][16];
#pragma unroll
  for (int g = 0; g < 3; ++g) {
    const ushort_t* wp = Wsel + (size_t)(g * H_ + jb + m16) * H_ + quad * 8;
#pragma unroll
    for (int kk = 0; kk < 16; ++kk)
      afrag[g][kk] = *(const short8*)(wp + kk * 32);
  }

  // Gate-math mapping: thread handles adjacent channels (c0,c1)=(2c,2c+1) at
  // batch b0, so the h/x stores pack into a single dword.
  const int b0 = tid & 31;
  const int c  = tid >> 5;      // 0..7
  const int c0 = 2 * c, c1 = 2 * c + 1;
  const float bxr0 = bih[0*H_ + jb + c0], bhr0 = bhh[0*H_ + jb + c0];
  const float bxz0 = bih[1*H_ + jb + c0], bhz0 = bhh[1*H_ + jb + c0];
  const float bxn0 = bih[2*H_ + jb + c0], bhn0 = bhh[2*H_ + jb + c0];
  const float bxr1 = bih[0*H_ + jb + c1], bhr1 = bhh[0*H_ + jb + c1];
  const float bxz1 = bih[1*H_ + jb + c1], bhz1 = bhh[1*H_ + jb + c1];
  const float bxn1 = bih[2*H_ + jb + c1], bhn1 = bhh[2*H_ + jb + c1];

  __syncthreads();

  for (int s = 0; s < T_; ++s) {
    f32x4 acc0 = {0.f, 0.f, 0.f, 0.f};
    f32x4 acc1 = acc0, acc2 = acc0;

    if (wave < 2) {
      // x-GEMM: input written by a previous kernel launch -> normal cached loads
      const ushort_t* src = xin + ((size_t)s * B_ + bcol) * H_ + quad * 8;
#pragma unroll
      for (int kk = 0; kk < 16; ++kk) {
        short8 bf = *(const short8*)(src + kk * 32);
        acc0 = __builtin_amdgcn_mfma_f32_16x16x32_bf16(afrag[0][kk], bf, acc0, 0, 0, 0);
        acc1 = __builtin_amdgcn_mfma_f32_16x16x32_bf16(afrag[1][kk], bf, acc1, 0, 0, 0);
        acc2 = __builtin_amdgcn_mfma_f32_16x16x32_bf16(afrag[2][kk], bf, acc2, 0, 0, 0);
      }
    } else {
      // h-GEMM: wait for all WGs to have published h(s)
      if (s > 0) {
        const int* fp = flags + (s - 1);
        while (__hip_atomic_load(fp, __ATOMIC_RELAXED, __HIP_MEMORY_SCOPE_AGENT) < G_)
          __builtin_amdgcn_s_sleep(1);
      }
      asm volatile("" ::: "memory");   // compiler barrier: no hoisting h loads above poll
      const ushort_t* src = hbuf + ((size_t)(s & 1) * B_ + bcol) * H_ + quad * 8;
#pragma unroll
      for (int kk = 0; kk < 16; ++kk) {
        const unsigned long long* p = (const unsigned long long*)(src + kk * 32);
        unsigned long long lo = __hip_atomic_load(p,     __ATOMIC_RELAXED, __HIP_MEMORY_SCOPE_AGENT);
        unsigned long long hi = __hip_atomic_load(p + 1, __ATOMIC_RELAXED, __HIP_MEMORY_SCOPE_AGENT);
        union { unsigned long long q[2]; short8 v; } u;
        u.q[0] = lo; u.q[1] = hi;
        short8 bf = u.v;
        acc0 = __builtin_amdgcn_mfma_f32_16x16x32_bf16(afrag[0][kk], bf, acc0, 0, 0, 0);
        acc1 = __builtin_amdgcn_mfma_f32_16x16x32_bf16(afrag[1][kk], bf, acc1, 0, 0, 0);
        acc2 = __builtin_amdgcn_mfma_f32_16x16x32_bf16(afrag[2][kk], bf, acc2, 0, 0, 0);
      }
    }

    // C/D layout: col = lane&15 (batch), row = quad*4 + reg
    float (*Gd)[33] = (wave < 2) ? Gx : Gh;
#pragma unroll
    for (int r = 0; r < 4; ++r) {
      Gd[ 0 + quad * 4 + r][bcol] = acc0[r];
      Gd[16 + quad * 4 + r][bcol] = acc1[r];
      Gd[32 + quad * 4 + r][bcol] = acc2[r];
    }
    __syncthreads();

    // Gate math (torch GRU, gate order r,z,n): n = tanh(xn + r*hn)
    ushort_t* hdst = hbuf + (size_t)((s + 1) & 1) * B_ * H_;
    float hv0, hv1;
    {
      float rr = 1.f / (1.f + __expf(-(Gx[c0][b0] + bxr0 + Gh[c0][b0] + bhr0)));
      float zz = 1.f / (1.f + __expf(-(Gx[16 + c0][b0] + bxz0 + Gh[16 + c0][b0] + bhz0)));
      float nn = tanhf(Gx[32 + c0][b0] + bxn0 + rr * (Gh[32 + c0][b0] + bhn0));
      hv0 = (1.f - zz) * nn + zz * hprev[c0][b0];
      hprev[c0][b0] = hv0;
    }
    {
      float rr = 1.f / (1.f + __expf(-(Gx[c1][b0] + bxr1 + Gh[c1][b0] + bhr1)));
      float zz = 1.f / (1.f + __expf(-(Gx[16 + c1][b0] + bxz1 + Gh[16 + c1][b0] + bhz1)));
      float nn = tanhf(Gx[32 + c1][b0] + bxn1 + rr * (Gh[32 + c1][b0] + bhn1));
      hv1 = (1.f - zz) * nn + zz * hprev[c1][b0];
      hprev[c1][b0] = hv1;
    }
    unsigned int pack = (unsigned int)f2bf(hv0) | ((unsigned int)f2bf(hv1) << 16);
    // coherent (LLC) publish of h; plain cached store for xout (next dispatch)
    __hip_atomic_store((unsigned int*)(hdst + (size_t)b0 * H_ + jb + c0), pack,
                       __ATOMIC_RELAXED, __HIP_MEMORY_SCOPE_AGENT);
    *(unsigned int*)(xout + ((size_t)s * B_ + b0) * H_ + jb + c0) = pack;

    // Drain every thread's h stores to the LLC, then one flag bump per WG.
    asm volatile("s_waitcnt vmcnt(0)" ::: "memory");
    __syncthreads();
    if (tid == 0)
      __hip_atomic_fetch_add(flags + s, 1, __ATOMIC_RELAXED, __HIP_MEMORY_SCOPE_AGENT);
  }
}

// ---------- mask (t >= len -> 0) + LayerNorm over H ----------
// mode 0: bf16 out, same [T][B][H] layout.  mode 1: fp32 out to d_out [B][T][H].
__global__ __launch_bounds__(256) void ln_mask(
    const ushort_t* __restrict__ xin,
    ushort_t* __restrict__ xout_bf,
    float* __restrict__ out_f32,
    const float* __restrict__ gamma,
    const float* __restrict__ beta,
    const int* __restrict__ seq_lens,
    int mode)
{
  const int lane = threadIdx.x & 63;
  const int wave = threadIdx.x >> 6;
  const int row  = blockIdx.x * 4 + wave;   // row = t*B_ + b
  const int t = row >> 5;
  const int b = row & 31;
  const int h0 = lane * 8;
  const bool valid = t < seq_lens[b];

  short8 raw = *(const short8*)(xin + (size_t)row * H_ + h0);
  float v[8];
#pragma unroll
  for (int j = 0; j < 8; ++j)
    v[j] = valid ? bf2f((ushort_t)raw[j]) : 0.f;

  float sum = 0.f, sq = 0.f;
#pragma unroll
  for (int j = 0; j < 8; ++j) { sum += v[j]; sq += v[j] * v[j]; }
#pragma unroll
  for (int off = 32; off > 0; off >>= 1) {
    sum += __shfl_xor(sum, off);
    sq  += __shfl_xor(sq, off);
  }
  float mu   = sum * (1.f / H_);
  float var  = sq * (1.f / H_) - mu * mu;
  float rstd = rsqrtf(var + 1e-5f);

  if (mode == 0) {
    short8 o;
#pragma unroll
    for (int j = 0; j < 8; ++j)
      o[j] = (short)f2bf((v[j] - mu) * rstd * gamma[h0 + j] + beta[h0 + j]);
    *(short8*)(xout_bf + (size_t)row * H_ + h0) = o;
  } else {
    float* dst = out_f32 + ((size_t)b * T_ + t) * H_ + h0;
#pragma unroll
    for (int j = 0; j < 8; ++j)
      dst[j] = (v[j] - mu) * rstd * gamma[h0 + j] + beta[h0 + j];
  }
}

// ---------- workspace layout (bytes) ----------
#define WIH_OFF 0u
#define WHH_OFF 6291456u            // 4*1536*512*2
#define XA_OFF  12582912u
#define XB_OFF  29360128u           // XA + 512*32*512*2
#define HB_OFF  46137344u           // XB + 16777216
#define FL_OFF  46399488u           // HB + 4*2*32*512*2
// total = 46407680 bytes (~44.3 MB)

extern "C" void kernel_launch(void* const* d_in, const int* in_sizes, int n_in,
                              void* d_out, int out_size, void* d_ws, size_t ws_size,
                              hipStream_t stream) {
  (void)in_sizes; (void)n_in; (void)out_size; (void)ws_size;
  const float* x     = (const float*)d_in[0];
  const float* Wih   = (const float*)d_in[1];
  const float* Whh   = (const float*)d_in[2];
  const float* bih   = (const float*)d_in[3];
  const float* bhh   = (const float*)d_in[4];
  const float* gamma = (const float*)d_in[5];
  const float* beta  = (const float*)d_in[6];
  const int*   seq   = (const int*)d_in[7];

  char* ws = (char*)d_ws;
  ushort_t* WihBf = (ushort_t*)(ws + WIH_OFF);
  ushort_t* WhhBf = (ushort_t*)(ws + WHH_OFF);
  ushort_t* xA    = (ushort_t*)(ws + XA_OFF);
  ushort_t* xB    = (ushort_t*)(ws + XB_OFF);
  ushort_t* hbuf  = (ushort_t*)(ws + HB_OFF);
  int*      flags = (int*)(ws + FL_OFF);

  // zero h ping-pong buffers + flags (harness poisons ws with 0xAA)
  hipMemsetAsync(ws + HB_OFF, 0, (FL_OFF - HB_OFF) + 4 * 512 * 4, stream);

  prep_w<<<3145728 / 256, 256, 0, stream>>>(Wih, Whh, WihBf, WhhBf);
  prep_x<<<8388608 / 256, 256, 0, stream>>>(x, xA);

  const int WM = 1536 * 512;  // elems per weight matrix
  // layer 0: xA -> xB
  gru_layer<<<G_, 256, 0, stream>>>(xA, xB, WihBf + 0 * WM, WhhBf + 0 * WM,
                                    bih + 0 * 1536, bhh + 0 * 1536,
                                    hbuf + 0 * 32768, flags + 0 * 512);
  // layer 1: xB -> xA
  gru_layer<<<G_, 256, 0, stream>>>(xB, xA, WihBf + 1 * WM, WhhBf + 1 * WM,
                                    bih + 1 * 1536, bhh + 1 * 1536,
                                    hbuf + 1 * 32768, flags + 1 * 512);
  // module 0 mask + LN: xA -> xB (bf16)
  ln_mask<<<4096, 256, 0, stream>>>(xA, xB, nullptr, gamma, beta, seq, 0);
  // layer 2: xB -> xA
  gru_layer<<<G_, 256, 0, stream>>>(xB, xA, WihBf + 2 * WM, WhhBf + 2 * WM,
                                    bih + 2 * 1536, bhh + 2 * 1536,
                                    hbuf + 2 * 32768, flags + 2 * 512);
  // layer 3: xA -> xB
  gru_layer<<<G_, 256, 0, stream>>>(xA, xB, WihBf + 3 * WM, WhhBf + 3 * WM,
                                    bih + 3 * 1536, bhh + 3 * 1536,
                                    hbuf + 3 * 32768, flags + 3 * 512);
  // module 1 mask + LN -> d_out fp32 [B][T][H]
  ln_mask<<<4096, 256, 0, stream>>>(xB, nullptr, (float*)d_out,
                                    gamma + 512, beta + 512, seq, 1);
}

// Round 3
// 4343.088 us; speedup vs baseline: 3.1894x; 3.1195x over previous
//
#include <hip/hip_runtime.h>

typedef unsigned short ushort_t;
typedef __attribute__((ext_vector_type(8))) short short8;   // 8 bf16 in 4 VGPRs
typedef __attribute__((ext_vector_type(4))) float f32x4;

#define B_ 32
#define T_ 512
#define H_ 512
#define CH_ 16     // output channels per GRU workgroup (32 WGs * 16 = 512)

// ---------- bf16 helpers ----------
__device__ __forceinline__ float bf2f(ushort_t u) {
  union { unsigned int i; float f; } v; v.i = ((unsigned int)u) << 16; return v.f;
}
__device__ __forceinline__ ushort_t f2bf(float f) {
  union { float fv; unsigned int i; } v; v.fv = f;
  unsigned int x = v.i;
  x += 0x7fffu + ((x >> 16) & 1u);   // round-to-nearest-even
  return (ushort_t)(x >> 16);
}

// ---------- flag helpers: per-step rows of 32 dwords, one per producer WG ----
// Publisher: one independent agent-scope store (no RMW, no hot-line cascade).
// Poller: 32-lane coalesced load + ballot.
__device__ __forceinline__ void poll_row(const int* row, int nf) {
  const int lane = threadIdx.x & 63;
  for (;;) {
    int v = 1;
    if (lane < nf)
      v = __hip_atomic_load(row + lane, __ATOMIC_RELAXED, __HIP_MEMORY_SCOPE_AGENT);
    if (__all(v != 0)) break;
    __builtin_amdgcn_s_sleep(1);
  }
  asm volatile("" ::: "memory");   // no hoisting data loads above the poll
}

// ---------- prep: fp32 weights -> bf16 ----------
__global__ void prep_w(const float* __restrict__ Wih, const float* __restrict__ Whh,
                       ushort_t* __restrict__ WihBf, ushort_t* __restrict__ WhhBf) {
  int i = blockIdx.x * 256 + threadIdx.x;
  WihBf[i] = f2bf(Wih[i]);
  WhhBf[i] = f2bf(Whh[i]);
}

// ---------- prep: x [B][T][H] fp32 -> [T][B][H] bf16 ----------
__global__ void prep_x(const float* __restrict__ x, ushort_t* __restrict__ xA) {
  int i = blockIdx.x * 256 + threadIdx.x;
  int h  = i & (H_ - 1);
  int tb = i >> 9;
  int b  = tb & (B_ - 1);
  int t  = tb >> 5;
  xA[i] = f2bf(x[((size_t)b * T_ + t) * H_ + h]);
}

// ---------- one GRU layer stage (32 WGs), runs inside the fused kernel ------
// All cross-WG data (h ping-pong, xout, flags) via agent-scope ops -> LLC,
// since per-XCD L2s are not coherent within a single dispatch.
__device__ void gru_stage(
    const ushort_t* __restrict__ xin, ushort_t* __restrict__ xout,
    const ushort_t* __restrict__ Wih, const ushort_t* __restrict__ Whh,
    const float* __restrict__ bih, const float* __restrict__ bhh,
    ushort_t* __restrict__ hbuf,
    int* __restrict__ selfFl,            // this layer's flag rows [T][32]
    const int* __restrict__ prodFl,      // producer flag rows (null for layer 0)
    int prodN, int wg,
    float (*Gx)[33], float (*Gh)[33], float (*hprev)[B_])
{
  const int tid   = threadIdx.x;
  const int lane  = tid & 63;
  const int wave  = tid >> 6;          // 0,1 = x-GEMM; 2,3 = h-GEMM
  const int jb    = wg * CH_;
  const int m16   = lane & 15;
  const int quad  = lane >> 4;
  const int bcol  = (wave & 1) * 16 + m16;

  hprev[tid >> 5][tid & 31]       = 0.0f;
  hprev[8 + (tid >> 5)][tid & 31] = 0.0f;

  // Weight fragments resident in registers (mfma A: A[m=lane&15][k=quad*8+j])
  const ushort_t* Wsel = (wave < 2) ? Wih : Whh;
  short8 afrag[3][16];
#pragma unroll
  for (int g = 0; g < 3; ++g) {
    const ushort_t* wp = Wsel + (size_t)(g * H_ + jb + m16) * H_ + quad * 8;
#pragma unroll
    for (int kk = 0; kk < 16; ++kk)
      afrag[g][kk] = *(const short8*)(wp + kk * 32);
  }

  const int b0 = tid & 31;
  const int c  = tid >> 5;
  const int c0 = 2 * c, c1 = 2 * c + 1;
  const float bxr0 = bih[0*H_ + jb + c0], bhr0 = bhh[0*H_ + jb + c0];
  const float bxz0 = bih[1*H_ + jb + c0], bhz0 = bhh[1*H_ + jb + c0];
  const float bxn0 = bih[2*H_ + jb + c0], bhn0 = bhh[2*H_ + jb + c0];
  const float bxr1 = bih[0*H_ + jb + c1], bhr1 = bhh[0*H_ + jb + c1];
  const float bxz1 = bih[1*H_ + jb + c1], bhz1 = bhh[1*H_ + jb + c1];
  const float bxn1 = bih[2*H_ + jb + c1], bhn1 = bhh[2*H_ + jb + c1];

  __syncthreads();

  for (int s = 0; s < T_; ++s) {
    f32x4 acc0 = {0.f, 0.f, 0.f, 0.f};
    f32x4 acc1 = acc0, acc2 = acc0;

    if (wave < 2) {
      const ushort_t* src = xin + ((size_t)s * B_ + bcol) * H_ + quad * 8;
      if (prodFl) {
        // gated on producer step-s flags; coherent loads (bypass stale L1/L2)
        poll_row(prodFl + s * 32, prodN);
#pragma unroll
        for (int kk = 0; kk < 16; ++kk) {
          const unsigned long long* p = (const unsigned long long*)(src + kk * 32);
          unsigned long long lo = __hip_atomic_load(p,     __ATOMIC_RELAXED, __HIP_MEMORY_SCOPE_AGENT);
          unsigned long long hi = __hip_atomic_load(p + 1, __ATOMIC_RELAXED, __HIP_MEMORY_SCOPE_AGENT);
          union { unsigned long long q[2]; short8 v; } u; u.q[0] = lo; u.q[1] = hi;
          acc0 = __builtin_amdgcn_mfma_f32_16x16x32_bf16(afrag[0][kk], u.v, acc0, 0, 0, 0);
          acc1 = __builtin_amdgcn_mfma_f32_16x16x32_bf16(afrag[1][kk], u.v, acc1, 0, 0, 0);
          acc2 = __builtin_amdgcn_mfma_f32_16x16x32_bf16(afrag[2][kk], u.v, acc2, 0, 0, 0);
        }
      } else {
        // layer 0: input from a prior dispatch -> plain cached loads
#pragma unroll
        for (int kk = 0; kk < 16; ++kk) {
          short8 bf = *(const short8*)(src + kk * 32);
          acc0 = __builtin_amdgcn_mfma_f32_16x16x32_bf16(afrag[0][kk], bf, acc0, 0, 0, 0);
          acc1 = __builtin_amdgcn_mfma_f32_16x16x32_bf16(afrag[1][kk], bf, acc1, 0, 0, 0);
          acc2 = __builtin_amdgcn_mfma_f32_16x16x32_bf16(afrag[2][kk], bf, acc2, 0, 0, 0);
        }
      }
    } else {
      if (s > 0) poll_row(selfFl + (s - 1) * 32, 32);
      const ushort_t* src = hbuf + ((size_t)(s & 1) * B_ + bcol) * H_ + quad * 8;
#pragma unroll
      for (int kk = 0; kk < 16; ++kk) {
        const unsigned long long* p = (const unsigned long long*)(src + kk * 32);
        unsigned long long lo = __hip_atomic_load(p,     __ATOMIC_RELAXED, __HIP_MEMORY_SCOPE_AGENT);
        unsigned long long hi = __hip_atomic_load(p + 1, __ATOMIC_RELAXED, __HIP_MEMORY_SCOPE_AGENT);
        union { unsigned long long q[2]; short8 v; } u; u.q[0] = lo; u.q[1] = hi;
        acc0 = __builtin_amdgcn_mfma_f32_16x16x32_bf16(afrag[0][kk], u.v, acc0, 0, 0, 0);
        acc1 = __builtin_amdgcn_mfma_f32_16x16x32_bf16(afrag[1][kk], u.v, acc1, 0, 0, 0);
        acc2 = __builtin_amdgcn_mfma_f32_16x16x32_bf16(afrag[2][kk], u.v, acc2, 0, 0, 0);
      }
    }

    // C/D layout: col = lane&15 (batch), row = quad*4 + reg
    float (*Gd)[33] = (wave < 2) ? Gx : Gh;
#pragma unroll
    for (int r = 0; r < 4; ++r) {
      Gd[ 0 + quad * 4 + r][bcol] = acc0[r];
      Gd[16 + quad * 4 + r][bcol] = acc1[r];
      Gd[32 + quad * 4 + r][bcol] = acc2[r];
    }
    __syncthreads();

    // Gate math (torch order r,z,n): n = tanh(xn + r*hn)
    ushort_t* hdst = hbuf + (size_t)((s + 1) & 1) * B_ * H_;
    float hv0, hv1;
    {
      float rr = 1.f / (1.f + __expf(-(Gx[c0][b0] + bxr0 + Gh[c0][b0] + bhr0)));
      float zz = 1.f / (1.f + __expf(-(Gx[16 + c0][b0] + bxz0 + Gh[16 + c0][b0] + bhz0)));
      float nn = tanhf(Gx[32 + c0][b0] + bxn0 + rr * (Gh[32 + c0][b0] + bhn0));
      hv0 = (1.f - zz) * nn + zz * hprev[c0][b0];
      hprev[c0][b0] = hv0;
    }
    {
      float rr = 1.f / (1.f + __expf(-(Gx[c1][b0] + bxr1 + Gh[c1][b0] + bhr1)));
      float zz = 1.f / (1.f + __expf(-(Gx[16 + c1][b0] + bxz1 + Gh[16 + c1][b0] + bhz1)));
      float nn = tanhf(Gx[32 + c1][b0] + bxn1 + rr * (Gh[32 + c1][b0] + bhn1));
      hv1 = (1.f - zz) * nn + zz * hprev[c1][b0];
      hprev[c1][b0] = hv1;
    }
    unsigned int pack = (unsigned int)f2bf(hv0) | ((unsigned int)f2bf(hv1) << 16);
    __hip_atomic_store((unsigned int*)(hdst + (size_t)b0 * H_ + jb + c0), pack,
                       __ATOMIC_RELAXED, __HIP_MEMORY_SCOPE_AGENT);
    __hip_atomic_store((unsigned int*)(xout + ((size_t)s * B_ + b0) * H_ + jb + c0), pack,
                       __ATOMIC_RELAXED, __HIP_MEMORY_SCOPE_AGENT);

    asm volatile("s_waitcnt vmcnt(0)" ::: "memory");   // drain h+x stores to LLC
    __syncthreads();
    if (tid == 0)
      __hip_atomic_store(selfFl + s * 32 + wg, 1,
                         __ATOMIC_RELAXED, __HIP_MEMORY_SCOPE_AGENT);
  }
}

// ---------- LN stage (8 WGs): mask (t>=len -> 0) + LayerNorm over H ----------
// wave v of WG w owns batch row b = w*4+v for every timestep.
__device__ void ln_stage(
    const ushort_t* __restrict__ xin,
    ushort_t* __restrict__ xout_bf,       // non-null for mid-stack LN (bf16 out)
    float* __restrict__ out_f32,          // non-null for final LN (fp32 d_out)
    const float* __restrict__ gamma, const float* __restrict__ beta,
    const int* __restrict__ seq,
    int* __restrict__ selfFl, const int* __restrict__ prodFl, int prodN, int wg)
{
  const int lane = threadIdx.x & 63;
  const int wv   = threadIdx.x >> 6;
  const int b    = wg * 4 + wv;
  const int len  = seq[b];
  const int h0   = lane * 8;

  float g[8], be[8];
#pragma unroll
  for (int j = 0; j < 8; ++j) { g[j] = gamma[h0 + j]; be[j] = beta[h0 + j]; }

  for (int s = 0; s < T_; ++s) {
    poll_row(prodFl + s * 32, prodN);
    const unsigned long long* p =
        (const unsigned long long*)(xin + ((size_t)s * B_ + b) * H_ + h0);
    unsigned long long lo = __hip_atomic_load(p,     __ATOMIC_RELAXED, __HIP_MEMORY_SCOPE_AGENT);
    unsigned long long hi = __hip_atomic_load(p + 1, __ATOMIC_RELAXED, __HIP_MEMORY_SCOPE_AGENT);
    union { unsigned long long q[2]; ushort_t u[8]; } un; un.q[0] = lo; un.q[1] = hi;
    const bool valid = s < len;
    float v[8];
#pragma unroll
    for (int j = 0; j < 8; ++j) v[j] = valid ? bf2f(un.u[j]) : 0.f;

    float sum = 0.f, sq = 0.f;
#pragma unroll
    for (int j = 0; j < 8; ++j) { sum += v[j]; sq += v[j] * v[j]; }
#pragma unroll
    for (int off = 32; off > 0; off >>= 1) {
      sum += __shfl_xor(sum, off);
      sq  += __shfl_xor(sq, off);
    }
    float mu   = sum * (1.f / H_);
    float var  = sq * (1.f / H_) - mu * mu;
    float rstd = rsqrtf(var + 1e-5f);

    if (xout_bf) {
      union { unsigned long long q[2]; ushort_t u[8]; } o;
#pragma unroll
      for (int j = 0; j < 8; ++j)
        o.u[j] = f2bf((v[j] - mu) * rstd * g[j] + be[j]);
      unsigned long long* q =
          (unsigned long long*)(xout_bf + ((size_t)s * B_ + b) * H_ + h0);
      __hip_atomic_store(q,     o.q[0], __ATOMIC_RELAXED, __HIP_MEMORY_SCOPE_AGENT);
      __hip_atomic_store(q + 1, o.q[1], __ATOMIC_RELAXED, __HIP_MEMORY_SCOPE_AGENT);
      asm volatile("s_waitcnt vmcnt(0)" ::: "memory");
      __syncthreads();
      if (threadIdx.x == 0)
        __hip_atomic_store(selfFl + s * 32 + wg, 1,
                           __ATOMIC_RELAXED, __HIP_MEMORY_SCOPE_AGENT);
    } else {
      float* dst = out_f32 + ((size_t)b * T_ + s) * H_ + h0;
#pragma unroll
      for (int j = 0; j < 8; ++j)
        dst[j] = (v[j] - mu) * rstd * g[j] + be[j];
      // no downstream consumer inside this dispatch; dispatch end flushes
    }
  }
}

// ---------- fused pipelined kernel: 6 stages, 144 WGs, one launch -----------
// Stage map: [0,32) L0  [32,64) L1  [64,72) LN0  [72,104) L2  [104,136) L3
//            [136,144) LN1 -> d_out
// Buffer aliasing (safe by flag causality): L2 writes xA (L0 consumed slot s
// before fl0[s] <= flLN0[s]); L3 writes xB (L1 consumed before fl1[s] <= fl2[s]).
__global__ __launch_bounds__(256, 1) void gru_mega(
    ushort_t* __restrict__ xA, ushort_t* __restrict__ xB,
    ushort_t* __restrict__ xC, ushort_t* __restrict__ xD,
    const ushort_t* __restrict__ WihBf, const ushort_t* __restrict__ WhhBf,
    const float* __restrict__ bih, const float* __restrict__ bhh,
    const float* __restrict__ gamma, const float* __restrict__ beta,
    const int* __restrict__ seq,
    ushort_t* __restrict__ hbase, int* __restrict__ flbase,
    float* __restrict__ out)
{
  __shared__ float Gx[48][33];
  __shared__ float Gh[48][33];
  __shared__ float hprev[CH_][B_];

  const int bid = blockIdx.x;
  const int FS = T_ * 32;               // flag ints per stage
  int* fl0   = flbase;
  int* fl1   = flbase + 1 * FS;
  int* flln0 = flbase + 2 * FS;
  int* fl2   = flbase + 3 * FS;
  int* fl3   = flbase + 4 * FS;
  const int WM = 3 * H_ * H_;           // elements per weight matrix
  const int HB = 2 * B_ * H_;           // elements per h ping-pong

  if (bid < 32) {
    gru_stage(xA, xB, WihBf, WhhBf, bih, bhh,
              hbase, fl0, nullptr, 0, bid, Gx, Gh, hprev);
  } else if (bid < 64) {
    gru_stage(xB, xC, WihBf + WM, WhhBf + WM, bih + 1536, bhh + 1536,
              hbase + HB, fl1, fl0, 32, bid - 32, Gx, Gh, hprev);
  } else if (bid < 72) {
    ln_stage(xC, xD, nullptr, gamma, beta, seq, flln0, fl1, 32, bid - 64);
  } else if (bid < 104) {
    gru_stage(xD, xA, WihBf + 2 * WM, WhhBf + 2 * WM, bih + 2 * 1536, bhh + 2 * 1536,
              hbase + 2 * HB, fl2, flln0, 8, bid - 72, Gx, Gh, hprev);
  } else if (bid < 136) {
    gru_stage(xA, xB, WihBf + 3 * WM, WhhBf + 3 * WM, bih + 3 * 1536, bhh + 3 * 1536,
              hbase + 3 * HB, fl3, fl2, 32, bid - 104, Gx, Gh, hprev);
  } else {
    ln_stage(xB, nullptr, out, gamma + H_, beta + H_, seq,
             nullptr, fl3, 32, bid - 136);
  }
}

// ---------- workspace layout (bytes) ----------
#define WIH_OFF 0u
#define WHH_OFF 6291456u              // 4*1536*512*2
#define XA_OFF  12582912u
#define XB_OFF  29360128u
#define XC_OFF  46137344u
#define XD_OFF  62914560u
#define HB_OFF  79691776u             // 4 * 2*32*512*2 = 262144
#define FL_OFF  79953920u             // 5 * 512*32*4  = 327680
// total = 80281600 (~76.6 MB)

extern "C" void kernel_launch(void* const* d_in, const int* in_sizes, int n_in,
                              void* d_out, int out_size, void* d_ws, size_t ws_size,
                              hipStream_t stream) {
  (void)in_sizes; (void)n_in; (void)out_size; (void)ws_size;
  const float* x     = (const float*)d_in[0];
  const float* Wih   = (const float*)d_in[1];
  const float* Whh   = (const float*)d_in[2];
  const float* bih   = (const float*)d_in[3];
  const float* bhh   = (const float*)d_in[4];
  const float* gamma = (const float*)d_in[5];
  const float* beta  = (const float*)d_in[6];
  const int*   seq   = (const int*)d_in[7];

  char* ws = (char*)d_ws;
  ushort_t* WihBf = (ushort_t*)(ws + WIH_OFF);
  ushort_t* WhhBf = (ushort_t*)(ws + WHH_OFF);
  ushort_t* xA    = (ushort_t*)(ws + XA_OFF);
  ushort_t* xB    = (ushort_t*)(ws + XB_OFF);
  ushort_t* xC    = (ushort_t*)(ws + XC_OFF);
  ushort_t* xD    = (ushort_t*)(ws + XD_OFF);
  ushort_t* hbase = (ushort_t*)(ws + HB_OFF);
  int*      flags = (int*)(ws + FL_OFF);

  // zero h ping-pong + flags (ws is poisoned 0xAA before every timed call)
  hipMemsetAsync(ws + HB_OFF, 0, 262144 + 327680, stream);

  prep_w<<<3145728 / 256, 256, 0, stream>>>(Wih, Whh, WihBf, WhhBf);
  prep_x<<<8388608 / 256, 256, 0, stream>>>(x, xA);

  gru_mega<<<144, 256, 0, stream>>>(xA, xB, xC, xD, WihBf, WhhBf,
                                    bih, bhh, gamma, beta, seq,
                                    hbase, flags, (float*)d_out);
}

// Round 4
// 3890.548 us; speedup vs baseline: 3.5604x; 1.1163x over previous
//
#include <hip/hip_runtime.h>

typedef unsigned short ushort_t;
typedef __attribute__((ext_vector_type(8))) short short8;   // 8 bf16 in 4 VGPRs
typedef __attribute__((ext_vector_type(4))) float f32x4;

#define B_ 32
#define T_ 512
#define H_ 512
#define CH_ 16     // output channels per GRU workgroup (32 WGs * 16 = 512)

// ---------- bf16 helpers ----------
__device__ __forceinline__ float bf2f(ushort_t u) {
  union { unsigned int i; float f; } v; v.i = ((unsigned int)u) << 16; return v.f;
}
__device__ __forceinline__ ushort_t f2bf(float f) {
  union { float fv; unsigned int i; } v; v.fv = f;
  unsigned int x = v.i;
  x += 0x7fffu + ((x >> 16) & 1u);   // round-to-nearest-even
  return (ushort_t)(x >> 16);
}

// fast gate activations: v_exp + v_rcp (approx, ~1ulp; bf16 output tolerant)
__device__ __forceinline__ float fsig(float a) {
  return __builtin_amdgcn_rcpf(1.f + __expf(-a));
}
__device__ __forceinline__ float ftanh(float a) {
  return 1.f - 2.f * __builtin_amdgcn_rcpf(1.f + __expf(2.f * a));  // sat: +/-1
}

// ---------- coherent (LLC) 16B load/store via sc0 sc1 ----------
__device__ __forceinline__ void cload16(short8& dst, const ushort_t* p) {
  asm volatile("global_load_dwordx4 %0, %1, off sc0 sc1"
               : "=v"(dst) : "v"(p) : "memory");
}
__device__ __forceinline__ void cstore16(const short8& v, ushort_t* p) {
  asm volatile("global_store_dwordx4 %1, %0, off sc0 sc1"
               :: "v"(v), "v"(p) : "memory");
}
#define WAIT_VM0 asm volatile("s_waitcnt vmcnt(0)" ::: "memory")
__device__ __forceinline__ void vfence(short8& v) { asm volatile("" : "+v"(v)); }

// ---------- flag rows: nf per-wave flags per step; poller = coalesced load + ballot
__device__ __forceinline__ void poll_row(const int* row, int nf) {
  const int lane = threadIdx.x & 63;
  if (nf > 64) {
    for (;;) {
      int a = __hip_atomic_load(row + lane,      __ATOMIC_RELAXED, __HIP_MEMORY_SCOPE_AGENT);
      int b = __hip_atomic_load(row + 64 + lane, __ATOMIC_RELAXED, __HIP_MEMORY_SCOPE_AGENT);
      if (__all(a != 0 && b != 0)) break;
      __builtin_amdgcn_s_sleep(1);
    }
  } else {
    for (;;) {
      int a = (lane < nf)
            ? __hip_atomic_load(row + lane, __ATOMIC_RELAXED, __HIP_MEMORY_SCOPE_AGENT) : 1;
      if (__all(a != 0)) break;
      __builtin_amdgcn_s_sleep(1);
    }
  }
  asm volatile("" ::: "memory");   // no hoisting data loads above the poll
}

// ---------- prep kernels ----------
__global__ void prep_w(const float* __restrict__ Wih, const float* __restrict__ Whh,
                       ushort_t* __restrict__ WihBf, ushort_t* __restrict__ WhhBf) {
  int i = blockIdx.x * 256 + threadIdx.x;
  WihBf[i] = f2bf(Wih[i]);
  WhhBf[i] = f2bf(Whh[i]);
}
__global__ void prep_x(const float* __restrict__ x, ushort_t* __restrict__ xA) {
  int i = blockIdx.x * 256 + threadIdx.x;
  int h  = i & (H_ - 1);
  int tb = i >> 9;
  int b  = tb & (B_ - 1);
  int t  = tb >> 5;
  xA[i] = f2bf(x[((size_t)b * T_ + t) * H_ + h]);
}

// ---------- one GRU layer stage (32 WGs) --------------------------------
// Per-step chain: poll -> 16x dwordx4 sc loads -> 48 MFMA -> LDS(parity) ->
// one __syncthreads -> gate math (regs) -> 2 dword agent stores -> vmcnt(0)
// -> per-wave flag. Gate LDS double-buffered by step parity => single barrier.
__device__ void gru_stage(
    const ushort_t* __restrict__ xin, ushort_t* __restrict__ xout,
    const ushort_t* __restrict__ Wih, const ushort_t* __restrict__ Whh,
    const float* __restrict__ bih, const float* __restrict__ bhh,
    ushort_t* __restrict__ hbuf,
    int* __restrict__ selfFl,            // [T][128] per-wave flags
    const int* __restrict__ prodFl,      // [T][prodN] (null for layer 0)
    int prodN, int wg,
    float (*Gbuf)[2][48][33])            // [parity][x/h][48][33]
{
  const int tid   = threadIdx.x;
  const int lane  = tid & 63;
  const int wave  = tid >> 6;          // 0,1 = x-GEMM; 2,3 = h-GEMM
  const int jb    = wg * CH_;
  const int m16   = lane & 15;
  const int quad  = lane >> 4;
  const int bcol  = (wave & 1) * 16 + m16;

  // Weight A-fragments resident in registers (A[m=lane&15][k=quad*8+j])
  const ushort_t* Wsel = (wave < 2) ? Wih : Whh;
  short8 afrag[3][16];
#pragma unroll
  for (int g = 0; g < 3; ++g) {
    const ushort_t* wp = Wsel + (size_t)(g * H_ + jb + m16) * H_ + quad * 8;
#pragma unroll
    for (int kk = 0; kk < 16; ++kk)
      afrag[g][kk] = *(const short8*)(wp + kk * 32);
  }

  const int b0 = tid & 31;
  const int c  = tid >> 5;
  const int c0 = 2 * c, c1 = 2 * c + 1;
  const float bxr0 = bih[0*H_ + jb + c0], bhr0 = bhh[0*H_ + jb + c0];
  const float bxz0 = bih[1*H_ + jb + c0], bhz0 = bhh[1*H_ + jb + c0];
  const float bxn0 = bih[2*H_ + jb + c0], bhn0 = bhh[2*H_ + jb + c0];
  const float bxr1 = bih[0*H_ + jb + c1], bhr1 = bhh[0*H_ + jb + c1];
  const float bxz1 = bih[1*H_ + jb + c1], bhz1 = bhh[1*H_ + jb + c1];
  const float bxn1 = bih[2*H_ + jb + c1], bhn1 = bhh[2*H_ + jb + c1];
  float hp0 = 0.f, hp1 = 0.f;          // per-thread h state in registers

  for (int s = 0; s < T_; ++s) {
    const int p = s & 1;
    f32x4 acc0 = {0.f, 0.f, 0.f, 0.f};
    f32x4 acc1 = acc0, acc2 = acc0;

    if (wave < 2) {
      const ushort_t* src = xin + ((size_t)s * B_ + bcol) * H_ + quad * 8;
      if (prodFl) {
        poll_row(prodFl + s * prodN, prodN);
        short8 bfr[16];
#pragma unroll
        for (int kk = 0; kk < 16; ++kk) cload16(bfr[kk], src + kk * 32);
        WAIT_VM0;
#pragma unroll
        for (int kk = 0; kk < 16; ++kk) {
          vfence(bfr[kk]);
          acc0 = __builtin_amdgcn_mfma_f32_16x16x32_bf16(afrag[0][kk], bfr[kk], acc0, 0, 0, 0);
          acc1 = __builtin_amdgcn_mfma_f32_16x16x32_bf16(afrag[1][kk], bfr[kk], acc1, 0, 0, 0);
          acc2 = __builtin_amdgcn_mfma_f32_16x16x32_bf16(afrag[2][kk], bfr[kk], acc2, 0, 0, 0);
        }
      } else {
        // layer 0: input from a prior dispatch -> plain cached loads
#pragma unroll
        for (int kk = 0; kk < 16; ++kk) {
          short8 bf = *(const short8*)(src + kk * 32);
          acc0 = __builtin_amdgcn_mfma_f32_16x16x32_bf16(afrag[0][kk], bf, acc0, 0, 0, 0);
          acc1 = __builtin_amdgcn_mfma_f32_16x16x32_bf16(afrag[1][kk], bf, acc1, 0, 0, 0);
          acc2 = __builtin_amdgcn_mfma_f32_16x16x32_bf16(afrag[2][kk], bf, acc2, 0, 0, 0);
        }
      }
    } else {
      if (s > 0) poll_row(selfFl + (s - 1) * 128, 128);
      const ushort_t* src = hbuf + ((size_t)p * B_ + bcol) * H_ + quad * 8;
      short8 bfr[16];
#pragma unroll
      for (int kk = 0; kk < 16; ++kk) cload16(bfr[kk], src + kk * 32);
      WAIT_VM0;
#pragma unroll
      for (int kk = 0; kk < 16; ++kk) {
        vfence(bfr[kk]);
        acc0 = __builtin_amdgcn_mfma_f32_16x16x32_bf16(afrag[0][kk], bfr[kk], acc0, 0, 0, 0);
        acc1 = __builtin_amdgcn_mfma_f32_16x16x32_bf16(afrag[1][kk], bfr[kk], acc1, 0, 0, 0);
        acc2 = __builtin_amdgcn_mfma_f32_16x16x32_bf16(afrag[2][kk], bfr[kk], acc2, 0, 0, 0);
      }
    }

    // C/D layout: col = lane&15 (batch), row = quad*4 + reg
    float (*Gd)[33] = Gbuf[p][(wave < 2) ? 0 : 1];
#pragma unroll
    for (int r = 0; r < 4; ++r) {
      Gd[ 0 + quad * 4 + r][bcol] = acc0[r];
      Gd[16 + quad * 4 + r][bcol] = acc1[r];
      Gd[32 + quad * 4 + r][bcol] = acc2[r];
    }
    __syncthreads();   // the ONLY barrier per step (parity buffers protect reuse)

    float (*Gx)[33] = Gbuf[p][0];
    float (*Gh)[33] = Gbuf[p][1];
    ushort_t* hdst = hbuf + (size_t)(p ^ 1) * B_ * H_;
    {
      float rr = fsig(Gx[c0][b0] + bxr0 + Gh[c0][b0] + bhr0);
      float zz = fsig(Gx[16 + c0][b0] + bxz0 + Gh[16 + c0][b0] + bhz0);
      float nn = ftanh(Gx[32 + c0][b0] + bxn0 + rr * (Gh[32 + c0][b0] + bhn0));
      hp0 = (1.f - zz) * nn + zz * hp0;
    }
    {
      float rr = fsig(Gx[c1][b0] + bxr1 + Gh[c1][b0] + bhr1);
      float zz = fsig(Gx[16 + c1][b0] + bxz1 + Gh[16 + c1][b0] + bhz1);
      float nn = ftanh(Gx[32 + c1][b0] + bxn1 + rr * (Gh[32 + c1][b0] + bhn1));
      hp1 = (1.f - zz) * nn + zz * hp1;
    }
    unsigned int pack = (unsigned int)f2bf(hp0) | ((unsigned int)f2bf(hp1) << 16);
    __hip_atomic_store((unsigned int*)(hdst + (size_t)b0 * H_ + jb + c0), pack,
                       __ATOMIC_RELAXED, __HIP_MEMORY_SCOPE_AGENT);
    __hip_atomic_store((unsigned int*)(xout + ((size_t)s * B_ + b0) * H_ + jb + c0), pack,
                       __ATOMIC_RELAXED, __HIP_MEMORY_SCOPE_AGENT);

    WAIT_VM0;                                   // this wave's stores now in LLC
    if (lane == 0)
      __hip_atomic_store(selfFl + s * 128 + wg * 4 + wave, 1,
                         __ATOMIC_RELAXED, __HIP_MEMORY_SCOPE_AGENT);
  }
}

// ---------- LN stage (8 WGs): mask (t>=len -> 0) + LayerNorm over H ----------
// wave v of WG w owns batch row b = w*4+v; waves fully independent (no barrier).
__device__ void ln_stage(
    const ushort_t* __restrict__ xin,
    ushort_t* __restrict__ xout_bf,       // non-null for mid-stack LN (bf16 out)
    float* __restrict__ out_f32,          // non-null for final LN (fp32 d_out)
    const float* __restrict__ gamma, const float* __restrict__ beta,
    const int* __restrict__ seq,
    int* __restrict__ selfFl,             // [T][32] per-wave(batch) flags
    const int* __restrict__ prodFl, int prodN, int wg)
{
  const int lane = threadIdx.x & 63;
  const int wv   = threadIdx.x >> 6;
  const int b    = wg * 4 + wv;
  const int len  = seq[b];
  const int h0   = lane * 8;

  float g[8], be[8];
#pragma unroll
  for (int j = 0; j < 8; ++j) { g[j] = gamma[h0 + j]; be[j] = beta[h0 + j]; }

  for (int s = 0; s < T_; ++s) {
    poll_row(prodFl + s * prodN, prodN);
    short8 raw;
    cload16(raw, xin + ((size_t)s * B_ + b) * H_ + h0);
    WAIT_VM0;
    vfence(raw);
    const bool valid = s < len;
    float v[8];
#pragma unroll
    for (int j = 0; j < 8; ++j) v[j] = valid ? bf2f((ushort_t)raw[j]) : 0.f;

    float sum = 0.f, sq = 0.f;
#pragma unroll
    for (int j = 0; j < 8; ++j) { sum += v[j]; sq += v[j] * v[j]; }
#pragma unroll
    for (int off = 32; off > 0; off >>= 1) {
      sum += __shfl_xor(sum, off);
      sq  += __shfl_xor(sq, off);
    }
    float mu   = sum * (1.f / H_);
    float var  = sq * (1.f / H_) - mu * mu;
    float rstd = rsqrtf(var + 1e-5f);

    if (xout_bf) {
      short8 o;
#pragma unroll
      for (int j = 0; j < 8; ++j)
        o[j] = (short)f2bf((v[j] - mu) * rstd * g[j] + be[j]);
      cstore16(o, xout_bf + ((size_t)s * B_ + b) * H_ + h0);
      WAIT_VM0;
      if (lane == 0)
        __hip_atomic_store(selfFl + s * 32 + b, 1,
                           __ATOMIC_RELAXED, __HIP_MEMORY_SCOPE_AGENT);
    } else {
      float* dst = out_f32 + ((size_t)b * T_ + s) * H_ + h0;
#pragma unroll
      for (int j = 0; j < 8; ++j)
        dst[j] = (v[j] - mu) * rstd * g[j] + be[j];
    }
  }
}

// ---------- fused pipelined kernel: 6 stages, 144 WGs, one launch -----------
// Stage map: [0,32) L0: xA->xB  [32,64) L1: xB->xC  [64,72) LN0: xC->xA
//            [72,104) L2: xA->xC  [104,136) L3: xC->xB  [136,144) LN1: xB->out
// Aliasing safe by flag causality: every writer of slot s is gated (via its
// input-flag chain) on the prior reader of slot s having consumed it.
__global__ __launch_bounds__(256, 1) void gru_mega(
    ushort_t* __restrict__ xA, ushort_t* __restrict__ xB, ushort_t* __restrict__ xC,
    const ushort_t* __restrict__ WihBf, const ushort_t* __restrict__ WhhBf,
    const float* __restrict__ bih, const float* __restrict__ bhh,
    const float* __restrict__ gamma, const float* __restrict__ beta,
    const int* __restrict__ seq,
    ushort_t* __restrict__ hbase, int* __restrict__ flbase,
    float* __restrict__ out)
{
  __shared__ float Gbuf[2][2][48][33];   // [parity][x/h]

  const int bid = blockIdx.x;
  const int GRUF = T_ * 128;            // flag ints per GRU stage
  const int LNF  = T_ * 32;             // flag ints per LN stage
  int* fl0   = flbase;
  int* fl1   = flbase + GRUF;
  int* flln0 = flbase + 2 * GRUF;
  int* fl2   = flbase + 2 * GRUF + LNF;
  int* fl3   = flbase + 3 * GRUF + LNF;
  const int WM  = 3 * H_ * H_;          // elements per weight matrix
  const int HBL = 2 * B_ * H_;          // elements per h ping-pong

  if (bid < 32) {
    gru_stage(xA, xB, WihBf, WhhBf, bih, bhh,
              hbase, fl0, nullptr, 0, bid, Gbuf);
  } else if (bid < 64) {
    gru_stage(xB, xC, WihBf + WM, WhhBf + WM, bih + 1536, bhh + 1536,
              hbase + HBL, fl1, fl0, 128, bid - 32, Gbuf);
  } else if (bid < 72) {
    ln_stage(xC, xA, nullptr, gamma, beta, seq, flln0, fl1, 128, bid - 64);
  } else if (bid < 104) {
    gru_stage(xA, xC, WihBf + 2 * WM, WhhBf + 2 * WM, bih + 2 * 1536, bhh + 2 * 1536,
              hbase + 2 * HBL, fl2, flln0, 32, bid - 72, Gbuf);
  } else if (bid < 136) {
    gru_stage(xC, xB, WihBf + 3 * WM, WhhBf + 3 * WM, bih + 3 * 1536, bhh + 3 * 1536,
              hbase + 3 * HBL, fl3, fl2, 128, bid - 104, Gbuf);
  } else {
    ln_stage(xB, nullptr, out, gamma + H_, beta + H_, seq,
             nullptr, fl3, 128, bid - 136);
  }
}

// ---------- workspace layout (bytes) ----------
#define WIH_OFF 0u
#define WHH_OFF 6291456u
#define XA_OFF  12582912u
#define XB_OFF  29360128u
#define XC_OFF  46137344u
#define HB_OFF  62914560u             // 4 * 2*32*512*2 = 262144
#define FL_OFF  63176704u             // 4*512*128*4 + 512*32*4 = 1114112
// total = 64290816 (~61.3 MB)

extern "C" void kernel_launch(void* const* d_in, const int* in_sizes, int n_in,
                              void* d_out, int out_size, void* d_ws, size_t ws_size,
                              hipStream_t stream) {
  (void)in_sizes; (void)n_in; (void)out_size; (void)ws_size;
  const float* x     = (const float*)d_in[0];
  const float* Wih   = (const float*)d_in[1];
  const float* Whh   = (const float*)d_in[2];
  const float* bih   = (const float*)d_in[3];
  const float* bhh   = (const float*)d_in[4];
  const float* gamma = (const float*)d_in[5];
  const float* beta  = (const float*)d_in[6];
  const int*   seq   = (const int*)d_in[7];

  char* ws = (char*)d_ws;
  ushort_t* WihBf = (ushort_t*)(ws + WIH_OFF);
  ushort_t* WhhBf = (ushort_t*)(ws + WHH_OFF);
  ushort_t* xA    = (ushort_t*)(ws + XA_OFF);
  ushort_t* xB    = (ushort_t*)(ws + XB_OFF);
  ushort_t* xC    = (ushort_t*)(ws + XC_OFF);
  ushort_t* hbase = (ushort_t*)(ws + HB_OFF);
  int*      flags = (int*)(ws + FL_OFF);

  // zero h ping-pong + flags (ws is poisoned 0xAA before every timed call)
  hipMemsetAsync(ws + HB_OFF, 0, 262144u + 1114112u, stream);

  prep_w<<<3145728 / 256, 256, 0, stream>>>(Wih, Whh, WihBf, WhhBf);
  prep_x<<<8388608 / 256, 256, 0, stream>>>(x, xA);

  gru_mega<<<144, 256, 0, stream>>>(xA, xB, xC, WihBf, WhhBf,
                                    bih, bhh, gamma, beta, seq,
                                    hbase, flags, (float*)d_out);
}